// Round 4
// baseline (346.592 us; speedup 1.0000x reference)
//
#include <hip/hip_runtime.h>
#include <hip/hip_fp16.h>
#include <math.h>

#define HW 240
#define PITCH 242           // complex pitch (float4-aligned rows)
#define IMG_PIX (HW*HW)     // 57600
#define NB 15               // kw/h blocks per image (passB/passC)
#define NBA 8               // 30-row blocks per image (passA)
#define TILE_ELEMS (240*16) // elements per blocked chunk

__device__ __forceinline__ float2 cmul(float2 a, float2 b){
    return make_float2(a.x*b.x - a.y*b.y, a.x*b.y + a.y*b.x);
}
__device__ __forceinline__ float2 cadd(float2 a, float2 b){
    return make_float2(a.x+b.x, a.y+b.y);
}
__device__ __forceinline__ float2 csub(float2 a, float2 b){
    return make_float2(a.x-b.x, a.y-b.y);
}
__device__ __forceinline__ __half2 f2h(float2 a){ return __floats2half2_rn(a.x, a.y); }
__device__ __forceinline__ float2 h2f(__half2 h){ return make_float2(__low2float(h), __high2float(h)); }

// Compiler-only fence: a wave's DS ops execute in issue order on the DS pipe,
// so intra-wave LDS exchanges need no s_barrier — only a scheduling fence.
// (Validated on this exact fft240 exchange pattern in rounds 2-3.)
__device__ __forceinline__ void wave_fence(){ __builtin_amdgcn_wave_barrier(); }

// ---------- 15-point DFT via Cooley-Tukey 3x5, all-constant twiddles ----------
template<int SIGN>
__device__ __forceinline__ void dft15(const float2* x, float2* X){
    const float S = (float)SIGN;
    const float s3 = 0.8660254037844387f;
    float2 y[5][3];
    #pragma unroll
    for (int n2 = 0; n2 < 5; ++n2){
        float2 a0 = x[n2], a1 = x[5+n2], a2 = x[10+n2];
        float2 t = cadd(a1, a2);
        float2 u = csub(a1, a2);
        float2 m = make_float2(a0.x - 0.5f*t.x, a0.y - 0.5f*t.y);
        float sx = S * s3;
        float2 s = make_float2(-sx*u.y, sx*u.x);
        y[n2][0] = cadd(a0, t);
        y[n2][1] = cadd(m, s);
        y[n2][2] = csub(m, s);
    }
    const float C15[9] = {1.f, 0.9135454576426009f, 0.6691306063588582f, 0.30901699437494745f,
                          -0.10452846326765346f, -0.5f, -0.8090169943749475f,
                          -0.9781476007338057f, -0.9781476007338057f};
    const float S15[9] = {0.f, 0.4067366430758004f, 0.7431448254773942f, 0.9510565162951535f,
                          0.9945218953682733f, 0.8660254037844387f, 0.5877852522924731f,
                          0.20791169081775931f, -0.20791169081775931f};
    #pragma unroll
    for (int n2 = 1; n2 < 5; ++n2){
        #pragma unroll
        for (int k1 = 1; k1 < 3; ++k1){
            const int e = n2*k1;
            y[n2][k1] = cmul(y[n2][k1], make_float2(C15[e], S*S15[e]));
        }
    }
    const float c1 = 0.30901699437494745f, s1 = 0.9510565162951535f;
    const float c2 = -0.8090169943749475f, s2 = 0.5877852522924731f;
    #pragma unroll
    for (int k1 = 0; k1 < 3; ++k1){
        float2 x0 = y[0][k1], x1 = y[1][k1], x2 = y[2][k1], x3 = y[3][k1], x4 = y[4][k1];
        float2 t1 = cadd(x1, x4), t3 = csub(x1, x4);
        float2 t2 = cadd(x2, x3), t4 = csub(x2, x3);
        X[k1] = make_float2(x0.x + t1.x + t2.x, x0.y + t1.y + t2.y);
        float2 u1 = make_float2(x0.x + c1*t1.x + c2*t2.x, x0.y + c1*t1.y + c2*t2.y);
        float2 u2 = make_float2(x0.x + c2*t1.x + c1*t2.x, x0.y + c2*t1.y + c1*t2.y);
        float2 v1 = make_float2(S*(s1*t3.x + s2*t4.x), S*(s1*t3.y + s2*t4.y));
        float2 v2 = make_float2(S*(s2*t3.x - s1*t4.x), S*(s2*t3.y - s1*t4.y));
        X[k1+3]  = make_float2(u1.x - v1.y, u1.y + v1.x);
        X[k1+12] = make_float2(u1.x + v1.y, u1.y - v1.x);
        X[k1+6]  = make_float2(u2.x - v2.y, u2.y + v2.x);
        X[k1+9]  = make_float2(u2.x + v2.y, u2.y - v2.x);
    }
}

// ---------- 16-point DFT via radix-4 x radix-4, all-constant twiddles ----------
template<int SIGN>
__device__ __forceinline__ void dft16(const float2* x, float2* X){
    const float S = (float)SIGN;
    float2 y[4][4];
    #pragma unroll
    for (int n2 = 0; n2 < 4; ++n2){
        float2 a0 = x[n2], a1 = x[4+n2], a2 = x[8+n2], a3 = x[12+n2];
        float2 t0 = cadd(a0,a2), t1 = csub(a0,a2);
        float2 t2 = cadd(a1,a3), t3 = csub(a1,a3);
        float2 it3 = make_float2(-S*t3.y, S*t3.x);
        y[n2][0] = cadd(t0,t2);
        y[n2][2] = csub(t0,t2);
        y[n2][1] = cadd(t1,it3);
        y[n2][3] = csub(t1,it3);
    }
    const float C16[10] = {1.f, 0.9238795325112867f, 0.7071067811865476f, 0.3826834323650898f,
                           0.f, -0.3826834323650898f, -0.7071067811865476f, -0.9238795325112867f,
                           -1.f, -0.9238795325112867f};
    const float S16[10] = {0.f, 0.3826834323650898f, 0.7071067811865476f, 0.9238795325112867f,
                           1.f, 0.9238795325112867f, 0.7071067811865476f, 0.3826834323650898f,
                           0.f, -0.3826834323650898f};
    #pragma unroll
    for (int n2 = 1; n2 < 4; ++n2){
        #pragma unroll
        for (int k1 = 1; k1 < 4; ++k1){
            const int e = n2*k1;
            y[n2][k1] = cmul(y[n2][k1], make_float2(C16[e], S*S16[e]));
        }
    }
    #pragma unroll
    for (int k1 = 0; k1 < 4; ++k1){
        float2 a0 = y[0][k1], a1 = y[1][k1], a2 = y[2][k1], a3 = y[3][k1];
        float2 t0 = cadd(a0,a2), t1 = csub(a0,a2);
        float2 t2 = cadd(a1,a3), t3 = csub(a1,a3);
        float2 it3 = make_float2(-S*t3.y, S*t3.x);
        X[k1]    = cadd(t0,t2);
        X[k1+8]  = csub(t0,t2);
        X[k1+4]  = cadd(t1,it3);
        X[k1+12] = csub(t1,it3);
    }
}

// Cooperative 240-point FFT core. v[a] = x[16a+b] preloaded in registers.
// Leaves results IN REGISTERS: for b<15, XX[m] = X[15m+b]. Row-local (rl)
// LDS exchange only => intra-wave => zero block barriers.
template<int SIGN>
__device__ __forceinline__ void fft240_core(float2 (*sm)[PITCH], float2* v,
                                            float2* XX, int rl, int b){
    const float TWOPI = 6.28318530717958647692f;
    wave_fence();                    // order vs any prior reads of this row
    float2 Y[15];
    dft15<SIGN>(v, Y);
    float2 step, tw = make_float2(1.0f, 0.0f);
    {
        float ang = (float)SIGN * TWOPI * (float)b * (1.0f/240.0f);
        __sincosf(ang, &step.y, &step.x);
    }
    #pragma unroll
    for (int d = 0; d < 15; ++d){
        sm[rl][b*15 + d] = cmul(Y[d], tw);
        tw = cmul(tw, step);
    }
    wave_fence();
    float2 Z[16];
    if (b < 15){
        #pragma unroll
        for (int bb = 0; bb < 16; ++bb) Z[bb] = sm[rl][bb*15 + b];
    }
    wave_fence();                    // gathers complete before row is reused
    if (b < 15) dft16<SIGN>(Z, XX);
}

// Full FFT: core + scatter so sm[rl][k] = X[k] afterwards (used by passA,
// whose Hermitian unpack needs cross-lane access to X[240-k]).
template<int SIGN>
__device__ __forceinline__ void fft240(float2 (*sm)[PITCH], float2* v, int rl, int b){
    float2 XX[16];
    fft240_core<SIGN>(sm, v, XX, rl, b);
    if (b < 15){
        #pragma unroll
        for (int m = 0; m < 16; ++m) sm[rl][15*m + b] = XX[m];
    }
    wave_fence();
}

// Pass A (REAL-PACKED, ZERO BARRIERS): 30 real rows per block as 15 complex
// FFTs. Rows 2r -> Re, 2r+1 -> Im, loaded DIRECTLY global->registers.
// Unpack via Hermitian split (exact):
//   Xa[k] = (X[k]+conj(X[-k]))/2,  Xb[k] = -i(X[k]-conj(X[-k]))/2.
// Store fp16 blocked: out[((img*15+kb)*240 + h)*16 + kwin], kw = kb*16+kwin.
__global__ __launch_bounds__(256) void passA_rowfft(const float* __restrict__ x,
                                                    __half2* __restrict__ out){
    __shared__ __align__(16) float2 sm[15][PITCH];
    int g = blockIdx.x, img = g / NBA, h0 = (g % NBA) * 30;
    int tid = threadIdx.x, rl = tid >> 4, b = tid & 15;
    if (tid >= 240) return;                 // no barriers anywhere: safe
    const float* r0 = x + (size_t)img * IMG_PIX + (size_t)(h0 + 2*rl) * HW;
    const float* r1 = r0 + HW;
    float2 v[15];
    #pragma unroll
    for (int a = 0; a < 15; ++a)
        v[a] = make_float2(r0[16*a + b], r1[16*a + b]);
    fft240<-1>(sm, v, rl, b);               // sm[rl][k] = packed spectrum
    #pragma unroll
    for (int kb = 0; kb < NB; ++kb){
        int k = kb*16 + b;
        int km = k ? 240 - k : 0;
        float2 P = sm[rl][k], Q = sm[rl][km];   // own row: intra-wave
        float2 Xa = make_float2(0.5f*(P.x + Q.x), 0.5f*(P.y - Q.y));
        float2 Xb = make_float2(0.5f*(P.y + Q.y), 0.5f*(Q.x - P.x));
        size_t o = ((size_t)(img*NB + kb)*HW + (h0 + 2*rl))*16 + b;
        out[o]      = f2h(Xa);              // row h0+2rl
        out[o + 16] = f2h(Xb);              // row h0+2rl+1
    }
}

// Pass B (IN-PLACE, ZERO BARRIERS): one chunk (16 kw cols x 240 h) per block.
// Wave w owns columns rl=4w..4w+3 end-to-end: direct global->reg loads,
// forward col FFT, DC combine IN REGISTERS (lane (rl,b) holds X[kh=15m+b] of
// kw=kw0+rl; per-m the 64 lanes read one full 64B line of U => coalesced),
// inverse col FFT, direct reg->global stores. In-place hazard is wave-local.
__global__ __launch_bounds__(256) void passB_col_dc_icol(__half2* __restrict__ io,
                                                         const float* __restrict__ under,
                                                         const float* __restrict__ Am){
    __shared__ __align__(16) float2 sm[16][PITCH];
    int g = blockIdx.x, img = g / NB, s = g % NB, kw0 = s * 16;
    int tid = threadIdx.x, rl = tid >> 4, b = tid & 15;
    __half2* chunk = io + (size_t)(img*NB + s) * TILE_ELEMS;   // [h][c]

    float2 v[15];                            // column rl, elements h=16a+b
    #pragma unroll
    for (int a = 0; a < 15; ++a)
        v[a] = h2f(chunk[(size_t)(16*a + b)*16 + rl]);   // chunk is L1-resident

    float2 XX[16];
    fft240_core<-1>(sm, v, XX, rl, b);       // XX[m] = X[kh=15m+b], col kw0+rl

    if (b < 15){
        const float* y0 = under + (size_t)img * (2*IMG_PIX);
        const float* y1 = y0 + IMG_PIX;
        #pragma unroll
        for (int m = 0; m < 16; ++m){
            size_t p = (size_t)(15*m + b) * HW + kw0 + rl;
            float sc = 1.0f - Am[p];
            XX[m] = make_float2(sc * XX[m].x + y0[p], sc * XX[m].y + y1[p]);
        }
        #pragma unroll
        for (int m = 0; m < 16; ++m) sm[rl][15*m + b] = XX[m];
    }
    wave_fence();                            // combined row visible to own wave

    float2 v2[15];
    #pragma unroll
    for (int a = 0; a < 15; ++a) v2[a] = sm[rl][16*a + b];
    float2 ZZ[16];
    fft240_core<+1>(sm, v2, ZZ, rl, b);      // ZZ[m] = 240*z[h=15m+b], col rl

    const float inv240 = 1.0f / 240.0f;
    if (b < 15){
        #pragma unroll
        for (int m = 0; m < 16; ++m)
            chunk[(size_t)(15*m + b)*16 + rl] =
                f2h(make_float2(ZZ[m].x*inv240, ZZ[m].y*inv240));
    }
}

// Pass C (ZERO BARRIERS): direct global->reg gather of row h0+rl across the 15
// blocked chunks (fully coalesced 256B/wave), inverse row FFT, abs*1/240,
// direct reg->global store (L2 merges; each wave covers whole lines over m).
__global__ __launch_bounds__(256) void passC_irow_abs(const __half2* __restrict__ in,
                                                      float* __restrict__ outp){
    __shared__ __align__(16) float2 sm[16][PITCH];
    int g = blockIdx.x, img = g / NB, h0 = (g % NB) * 16;
    int tid = threadIdx.x, rl = tid >> 4, b = tid & 15;
    float2 v[15];
    #pragma unroll
    for (int a = 0; a < 15; ++a)
        v[a] = h2f(in[((size_t)(img*NB + a)*HW + h0 + rl)*16 + b]);
    float2 XX[16];
    fft240_core<+1>(sm, v, XX, rl, b);       // XX[m] = 240*z[w=15m+b], row h0+rl
    const float inv240 = 1.0f / 240.0f;
    float* dst = outp + (size_t)img * IMG_PIX + (size_t)(h0 + rl) * HW;
    if (b < 15){
        #pragma unroll
        for (int m = 0; m < 16; ++m){
            float2 X = XX[m];
            dst[15*m + b] = sqrtf(X.x*X.x + X.y*X.y) * inv240;
        }
    }
}

extern "C" void kernel_launch(void* const* d_in, const int* in_sizes, int n_in,
                              void* d_out, int out_size, void* d_ws, size_t ws_size,
                              hipStream_t stream){
    const float* T2   = (const float*)d_in[0];   // [256,1,240,240] f32
    const float* U    = (const float*)d_in[1];   // [256,2,240,240] f32
    const float* Am   = (const float*)d_in[2];   // [240,240] f32
    float* out        = (float*)d_out;           // [256,1,240,240] f32

    const int B = 256;
    __half2* i1 = (__half2*)d_ws;                // single 59 MB fp16 intermediate

    dim3 block(256);
    passA_rowfft     <<<dim3(B * NBA), block, 0, stream>>>(T2, i1);
    passB_col_dc_icol<<<dim3(B * NB),  block, 0, stream>>>(i1, U, Am);
    passC_irow_abs   <<<dim3(B * NB),  block, 0, stream>>>(i1, out);
}

// Round 5
// 333.310 us; speedup vs baseline: 1.0398x; 1.0398x over previous
//
#include <hip/hip_runtime.h>
#include <hip/hip_fp16.h>
#include <math.h>

#define HW 240
#define PITCH 242           // complex pitch (float4-aligned rows)
#define IMG_PIX (HW*HW)     // 57600
#define NB 15               // kw/h blocks per image (passB/passC)
#define NBA 8               // 30-row blocks per image (passA)
#define TILE_ELEMS (240*16) // elements per blocked chunk
#define CHA 4               // chunks per block, passA  (2048/4 = 512 blocks)
#define CHB 3               // chunks per block, passB  (3840/3 = 1280 blocks)
#define CHC 3               // chunks per block, passC  (3840/3 = 1280 blocks)

__device__ __forceinline__ float2 cmul(float2 a, float2 b){
    return make_float2(a.x*b.x - a.y*b.y, a.x*b.y + a.y*b.x);
}
__device__ __forceinline__ float2 cadd(float2 a, float2 b){
    return make_float2(a.x+b.x, a.y+b.y);
}
__device__ __forceinline__ float2 csub(float2 a, float2 b){
    return make_float2(a.x-b.x, a.y-b.y);
}
__device__ __forceinline__ __half2 f2h(float2 a){ return __floats2half2_rn(a.x, a.y); }
__device__ __forceinline__ float2 h2f(__half2 h){ return make_float2(__low2float(h), __high2float(h)); }

// Compiler-only fence: a wave's DS ops execute in issue order on the DS pipe,
// so intra-wave LDS exchanges need no s_barrier (validated R2-R4 on this fft).
__device__ __forceinline__ void wave_fence(){ __builtin_amdgcn_wave_barrier(); }

// Block barrier that drains LDS ONLY (lgkmcnt), leaving global prefetch loads
// in flight across it (vmcnt untouched). __syncthreads would drain vmcnt(0)
// and kill the software pipeline. "memory" clobbers fence the compiler.
__device__ __forceinline__ void lds_barrier(){
    asm volatile("s_waitcnt lgkmcnt(0)" ::: "memory");
    __builtin_amdgcn_s_barrier();
    asm volatile("" ::: "memory");
}

// ---------- 15-point DFT via Cooley-Tukey 3x5, all-constant twiddles ----------
template<int SIGN>
__device__ __forceinline__ void dft15(const float2* x, float2* X){
    const float S = (float)SIGN;
    const float s3 = 0.8660254037844387f;
    float2 y[5][3];
    #pragma unroll
    for (int n2 = 0; n2 < 5; ++n2){
        float2 a0 = x[n2], a1 = x[5+n2], a2 = x[10+n2];
        float2 t = cadd(a1, a2);
        float2 u = csub(a1, a2);
        float2 m = make_float2(a0.x - 0.5f*t.x, a0.y - 0.5f*t.y);
        float sx = S * s3;
        float2 s = make_float2(-sx*u.y, sx*u.x);
        y[n2][0] = cadd(a0, t);
        y[n2][1] = cadd(m, s);
        y[n2][2] = csub(m, s);
    }
    const float C15[9] = {1.f, 0.9135454576426009f, 0.6691306063588582f, 0.30901699437494745f,
                          -0.10452846326765346f, -0.5f, -0.8090169943749475f,
                          -0.9781476007338057f, -0.9781476007338057f};
    const float S15[9] = {0.f, 0.4067366430758004f, 0.7431448254773942f, 0.9510565162951535f,
                          0.9945218953682733f, 0.8660254037844387f, 0.5877852522924731f,
                          0.20791169081775931f, -0.20791169081775931f};
    #pragma unroll
    for (int n2 = 1; n2 < 5; ++n2){
        #pragma unroll
        for (int k1 = 1; k1 < 3; ++k1){
            const int e = n2*k1;
            y[n2][k1] = cmul(y[n2][k1], make_float2(C15[e], S*S15[e]));
        }
    }
    const float c1 = 0.30901699437494745f, s1 = 0.9510565162951535f;
    const float c2 = -0.8090169943749475f, s2 = 0.5877852522924731f;
    #pragma unroll
    for (int k1 = 0; k1 < 3; ++k1){
        float2 x0 = y[0][k1], x1 = y[1][k1], x2 = y[2][k1], x3 = y[3][k1], x4 = y[4][k1];
        float2 t1 = cadd(x1, x4), t3 = csub(x1, x4);
        float2 t2 = cadd(x2, x3), t4 = csub(x2, x3);
        X[k1] = make_float2(x0.x + t1.x + t2.x, x0.y + t1.y + t2.y);
        float2 u1 = make_float2(x0.x + c1*t1.x + c2*t2.x, x0.y + c1*t1.y + c2*t2.y);
        float2 u2 = make_float2(x0.x + c2*t1.x + c1*t2.x, x0.y + c2*t1.y + c1*t2.y);
        float2 v1 = make_float2(S*(s1*t3.x + s2*t4.x), S*(s1*t3.y + s2*t4.y));
        float2 v2 = make_float2(S*(s2*t3.x - s1*t4.x), S*(s2*t3.y - s1*t4.y));
        X[k1+3]  = make_float2(u1.x - v1.y, u1.y + v1.x);
        X[k1+12] = make_float2(u1.x + v1.y, u1.y - v1.x);
        X[k1+6]  = make_float2(u2.x - v2.y, u2.y + v2.x);
        X[k1+9]  = make_float2(u2.x + v2.y, u2.y - v2.x);
    }
}

// ---------- 16-point DFT via radix-4 x radix-4, all-constant twiddles ----------
template<int SIGN>
__device__ __forceinline__ void dft16(const float2* x, float2* X){
    const float S = (float)SIGN;
    float2 y[4][4];
    #pragma unroll
    for (int n2 = 0; n2 < 4; ++n2){
        float2 a0 = x[n2], a1 = x[4+n2], a2 = x[8+n2], a3 = x[12+n2];
        float2 t0 = cadd(a0,a2), t1 = csub(a0,a2);
        float2 t2 = cadd(a1,a3), t3 = csub(a1,a3);
        float2 it3 = make_float2(-S*t3.y, S*t3.x);
        y[n2][0] = cadd(t0,t2);
        y[n2][2] = csub(t0,t2);
        y[n2][1] = cadd(t1,it3);
        y[n2][3] = csub(t1,it3);
    }
    const float C16[10] = {1.f, 0.9238795325112867f, 0.7071067811865476f, 0.3826834323650898f,
                           0.f, -0.3826834323650898f, -0.7071067811865476f, -0.9238795325112867f,
                           -1.f, -0.9238795325112867f};
    const float S16[10] = {0.f, 0.3826834323650898f, 0.7071067811865476f, 0.9238795325112867f,
                           1.f, 0.9238795325112867f, 0.7071067811865476f, 0.3826834323650898f,
                           0.f, -0.3826834323650898f};
    #pragma unroll
    for (int n2 = 1; n2 < 4; ++n2){
        #pragma unroll
        for (int k1 = 1; k1 < 4; ++k1){
            const int e = n2*k1;
            y[n2][k1] = cmul(y[n2][k1], make_float2(C16[e], S*S16[e]));
        }
    }
    #pragma unroll
    for (int k1 = 0; k1 < 4; ++k1){
        float2 a0 = y[0][k1], a1 = y[1][k1], a2 = y[2][k1], a3 = y[3][k1];
        float2 t0 = cadd(a0,a2), t1 = csub(a0,a2);
        float2 t2 = cadd(a1,a3), t3 = csub(a1,a3);
        float2 it3 = make_float2(-S*t3.y, S*t3.x);
        X[k1]    = cadd(t0,t2);
        X[k1+8]  = csub(t0,t2);
        X[k1+4]  = cadd(t1,it3);
        X[k1+12] = csub(t1,it3);
    }
}

// Cooperative 240-point FFT core. v[a] = x[16a+b] preloaded in registers.
// Leaves results IN REGISTERS: for b<15, XX[m] = X[15m+b]. Row-local (rl)
// LDS exchange only => intra-wave => no block barriers inside.
template<int SIGN>
__device__ __forceinline__ void fft240_core(float2 (*sm)[PITCH], float2* v,
                                            float2* XX, int rl, int b){
    const float TWOPI = 6.28318530717958647692f;
    wave_fence();                    // order vs any prior reads of this row
    float2 Y[15];
    dft15<SIGN>(v, Y);
    float2 step, tw = make_float2(1.0f, 0.0f);
    {
        float ang = (float)SIGN * TWOPI * (float)b * (1.0f/240.0f);
        __sincosf(ang, &step.y, &step.x);
    }
    #pragma unroll
    for (int d = 0; d < 15; ++d){
        sm[rl][b*15 + d] = cmul(Y[d], tw);
        tw = cmul(tw, step);
    }
    wave_fence();
    float2 Z[16];
    if (b < 15){
        #pragma unroll
        for (int bb = 0; bb < 16; ++bb) Z[bb] = sm[rl][bb*15 + b];
    }
    wave_fence();                    // gathers complete before row is reused
    if (b < 15) dft16<SIGN>(Z, XX);
}

// Full FFT: core + scatter so sm[rl][k] = X[k] (passA's Hermitian unpack
// needs cross-lane access to X[240-k]).
template<int SIGN>
__device__ __forceinline__ void fft240(float2 (*sm)[PITCH], float2* v, int rl, int b){
    float2 XX[16];
    fft240_core<SIGN>(sm, v, XX, rl, b);
    if (b < 15){
        #pragma unroll
        for (int m = 0; m < 16; ++m) sm[rl][15*m + b] = XX[m];
    }
    wave_fence();
}

// Pass A (REAL-PACKED, PIPELINED, ZERO BARRIERS): CHA chunks of 30 real rows
// per block; rows 2r->Re, 2r+1->Im; direct coalesced global->reg loads, next
// chunk prefetched during current FFT. Hermitian unpack is exact.
__global__ __launch_bounds__(256) void passA_rowfft(const float* __restrict__ x,
                                                    __half2* __restrict__ out){
    __shared__ __align__(16) float2 sm[15][PITCH];
    int g = blockIdx.x;
    int tid = threadIdx.x, rl = tid >> 4, b = tid & 15;
    if (tid >= 240) return;                 // no block barriers: safe
    float2 v[15];
    {
        int c = g*CHA; int img = c / NBA, h0 = (c % NBA) * 30;
        const float* r0 = x + (size_t)img * IMG_PIX + (size_t)(h0 + 2*rl) * HW;
        #pragma unroll
        for (int a = 0; a < 15; ++a)
            v[a] = make_float2(r0[16*a + b], r0[HW + 16*a + b]);
    }
    for (int t = 0; t < CHA; ++t){
        int c = g*CHA + t; int img = c / NBA, h0 = (c % NBA) * 30;
        float2 nv[15];
        if (t+1 < CHA){                     // prefetch next chunk early
            int c2 = c + 1; int img2 = c2 / NBA, h02 = (c2 % NBA) * 30;
            const float* r0 = x + (size_t)img2 * IMG_PIX + (size_t)(h02 + 2*rl) * HW;
            #pragma unroll
            for (int a = 0; a < 15; ++a)
                nv[a] = make_float2(r0[16*a + b], r0[HW + 16*a + b]);
        }
        asm volatile("" ::: "memory");      // pin prefetch issue point
        fft240<-1>(sm, v, rl, b);           // sm[rl][k] = packed spectrum
        #pragma unroll
        for (int kb = 0; kb < NB; ++kb){
            int k = kb*16 + b;
            int km = k ? 240 - k : 0;
            float2 P = sm[rl][k], Q = sm[rl][km];   // own row: intra-wave
            float2 Xa = make_float2(0.5f*(P.x + Q.x), 0.5f*(P.y - Q.y));
            float2 Xb = make_float2(0.5f*(P.y + Q.y), 0.5f*(Q.x - P.x));
            size_t o = ((size_t)(img*NB + kb)*HW + (h0 + 2*rl))*16 + b;
            out[o]      = f2h(Xa);          // row h0+2rl
            out[o + 16] = f2h(Xb);          // row h0+2rl+1
        }
        if (t+1 < CHA){
            #pragma unroll
            for (int a = 0; a < 15; ++a) v[a] = nv[a];
        }
    }
}

// Pass B (IN-PLACE, PIPELINED): CHB chunks (16 kw cols x 240 h) per block.
// Coalesced float4 stage -> LDS (R2 pattern); chunk t+1 raw regs + U(t+1)
// regs prefetched early and kept in flight across lds_barrier (lgkm-only).
// Combine is the R2 LDS-RMW (coalesced U reads); stores direct from regs.
__global__ __launch_bounds__(256) void passB_col_dc_icol(__half2* __restrict__ io,
                                                         const float* __restrict__ under,
                                                         const float* __restrict__ Am){
    __shared__ __align__(16) float2 sm[16][PITCH];
    int g = blockIdx.x;
    int tid = threadIdx.x, rl = tid >> 4, b = tid & 15;
    float4 raw[4];
    float y0r[15], y1r[15];
    {   // prologue: chunk c0 data + U(c0)
        int c = g*CHB;
        const __half2* chunk0 = io + (size_t)c * TILE_ELEMS;
        if (tid < 240){
            #pragma unroll
            for (int jj = 0; jj < 4; ++jj)
                raw[jj] = *(const float4*)(chunk0 + 4*(jj*240 + tid));
        }
        int img = c / NB, kw0 = (c % NB) * 16;
        const float* y0 = under + (size_t)img * (2*IMG_PIX);
        #pragma unroll
        for (int j = 0; j < 15; ++j){
            size_t p = (size_t)(j*16 + rl) * HW + kw0 + b;
            y0r[j] = y0[p]; y1r[j] = y0[IMG_PIX + p];
        }
    }
    asm volatile("" ::: "memory");
    const float inv240 = 1.0f / 240.0f;
    for (int t = 0; t < CHB; ++t){
        int c = g*CHB + t;
        int s = c % NB, kw0 = s * 16;
        __half2* chunk = io + (size_t)c * TILE_ELEMS;
        if (t) lds_barrier();               // B0: prev iter's LDS reads done
        if (tid < 240){                     // scatter raw -> sm[c][h]
            #pragma unroll
            for (int jj = 0; jj < 4; ++jj){
                int k = jj*240 + tid;
                const __half2* hp = (const __half2*)&raw[jj];
                int col = k >> 2;
                int r0 = (4*k) & 15;
                #pragma unroll
                for (int i = 0; i < 4; ++i) sm[r0 + i][col] = h2f(hp[i]);
            }
        }
        if (t+1 < CHB){                     // prefetch next chunk's raw
            const __half2* chunk2 = io + (size_t)(c+1) * TILE_ELEMS;
            if (tid < 240){
                #pragma unroll
                for (int jj = 0; jj < 4; ++jj)
                    raw[jj] = *(const float4*)(chunk2 + 4*(jj*240 + tid));
            }
        }
        asm volatile("" ::: "memory");      // pin prefetch issue point
        lds_barrier();                      // B1: stage visible
        float2 v[15];
        #pragma unroll
        for (int a = 0; a < 15; ++a) v[a] = sm[rl][16*a + b];
        float2 XX[16];
        fft240_core<-1>(sm, v, XX, rl, b);  // XX[m] = X[kh=15m+b], col kw0+rl
        if (b < 15){
            #pragma unroll
            for (int m = 0; m < 16; ++m) sm[rl][15*m + b] = XX[m];
        }
        lds_barrier();                      // B2: spectrum visible cross-wave
        #pragma unroll
        for (int j = 0; j < 15; ++j){       // DC combine, coalesced U pattern
            int kh = j*16 + rl;
            size_t p = (size_t)kh * HW + kw0 + b;
            float sc = 1.0f - Am[p];
            float2 X = sm[b][kh];
            sm[b][kh] = make_float2(sc * X.x + y0r[j], sc * X.y + y1r[j]);
        }
        if (t+1 < CHB){                     // prefetch U(t+1) after last use
            int c2 = c + 1; int img2 = c2 / NB, kw02 = (c2 % NB) * 16;
            const float* y0 = under + (size_t)img2 * (2*IMG_PIX);
            #pragma unroll
            for (int j = 0; j < 15; ++j){
                size_t p = (size_t)(j*16 + rl) * HW + kw02 + b;
                y0r[j] = y0[p]; y1r[j] = y0[IMG_PIX + p];
            }
        }
        asm volatile("" ::: "memory");      // pin U prefetch issue point
        lds_barrier();                      // B3: combine visible cross-wave
        float2 v2[15];
        #pragma unroll
        for (int a = 0; a < 15; ++a) v2[a] = sm[rl][16*a + b];
        float2 ZZ[16];
        fft240_core<+1>(sm, v2, ZZ, rl, b); // ZZ[m] = 240*z[h=15m+b], col rl
        if (b < 15){                        // direct in-reg store (L2 merges)
            #pragma unroll
            for (int m = 0; m < 16; ++m)
                chunk[(size_t)(15*m + b)*16 + rl] =
                    f2h(make_float2(ZZ[m].x*inv240, ZZ[m].y*inv240));
        }
    }
}

// Pass C (PIPELINED, ZERO BARRIERS): CHC row tiles per block; direct coalesced
// global->reg gather across the 15 chunks, inverse row FFT, abs*1/240, direct
// reg->global store; next tile prefetched during current FFT.
__global__ __launch_bounds__(256) void passC_irow_abs(const __half2* __restrict__ in,
                                                      float* __restrict__ outp){
    __shared__ __align__(16) float2 sm[16][PITCH];
    int g = blockIdx.x;
    int tid = threadIdx.x, rl = tid >> 4, b = tid & 15;
    float2 v[15];
    {
        int c = g*CHC; int img = c / NB, h0 = (c % NB) * 16;
        #pragma unroll
        for (int a = 0; a < 15; ++a)
            v[a] = h2f(in[((size_t)(img*NB + a)*HW + h0 + rl)*16 + b]);
    }
    const float inv240 = 1.0f / 240.0f;
    for (int t = 0; t < CHC; ++t){
        int c = g*CHC + t; int img = c / NB, h0 = (c % NB) * 16;
        float2 nv[15];
        if (t+1 < CHC){                     // prefetch next tile early
            int c2 = c + 1; int img2 = c2 / NB, h02 = (c2 % NB) * 16;
            #pragma unroll
            for (int a = 0; a < 15; ++a)
                nv[a] = h2f(in[((size_t)(img2*NB + a)*HW + h02 + rl)*16 + b]);
        }
        asm volatile("" ::: "memory");      // pin prefetch issue point
        float2 XX[16];
        fft240_core<+1>(sm, v, XX, rl, b);  // XX[m] = 240*z[w=15m+b], row h0+rl
        float* dst = outp + (size_t)img * IMG_PIX + (size_t)(h0 + rl) * HW;
        if (b < 15){
            #pragma unroll
            for (int m = 0; m < 16; ++m){
                float2 X = XX[m];
                dst[15*m + b] = sqrtf(X.x*X.x + X.y*X.y) * inv240;
            }
        }
        if (t+1 < CHC){
            #pragma unroll
            for (int a = 0; a < 15; ++a) v[a] = nv[a];
        }
    }
}

extern "C" void kernel_launch(void* const* d_in, const int* in_sizes, int n_in,
                              void* d_out, int out_size, void* d_ws, size_t ws_size,
                              hipStream_t stream){
    const float* T2   = (const float*)d_in[0];   // [256,1,240,240] f32
    const float* U    = (const float*)d_in[1];   // [256,2,240,240] f32
    const float* Am   = (const float*)d_in[2];   // [240,240] f32
    float* out        = (float*)d_out;           // [256,1,240,240] f32

    const int B = 256;
    __half2* i1 = (__half2*)d_ws;                // single 59 MB fp16 intermediate

    dim3 block(256);
    passA_rowfft     <<<dim3(B * NBA / CHA), block, 0, stream>>>(T2, i1);
    passB_col_dc_icol<<<dim3(B * NB  / CHB), block, 0, stream>>>(i1, U, Am);
    passC_irow_abs   <<<dim3(B * NB  / CHC), block, 0, stream>>>(i1, out);
}

// Round 6
// 294.173 us; speedup vs baseline: 1.1782x; 1.1330x over previous
//
#include <hip/hip_runtime.h>
#include <hip/hip_fp16.h>
#include <math.h>

#define HW 240
#define PITCH 242           // complex pitch (float4-aligned rows)
#define IMG_PIX (HW*HW)     // 57600
#define NB 15               // kw/h blocks per image (passB/passC)
#define NBA 8               // 30-row blocks per image (passA)
#define TILE_ELEMS (240*16) // elements per blocked chunk
#define CHA 4               // chunks per block, passA  (2048/4 = 512 blocks)
#define CHC 3               // chunks per block, passC  (3840/3 = 1280 blocks)

__device__ __forceinline__ float2 cmul(float2 a, float2 b){
    return make_float2(a.x*b.x - a.y*b.y, a.x*b.y + a.y*b.x);
}
__device__ __forceinline__ float2 cadd(float2 a, float2 b){
    return make_float2(a.x+b.x, a.y+b.y);
}
__device__ __forceinline__ float2 csub(float2 a, float2 b){
    return make_float2(a.x-b.x, a.y-b.y);
}
__device__ __forceinline__ __half2 f2h(float2 a){ return __floats2half2_rn(a.x, a.y); }
__device__ __forceinline__ float2 h2f(__half2 h){ return make_float2(__low2float(h), __high2float(h)); }

// Compiler-only fence: a wave's DS ops execute in issue order on the DS pipe,
// so intra-wave LDS exchanges need no s_barrier (validated R2-R5 on this fft).
__device__ __forceinline__ void wave_fence(){ __builtin_amdgcn_wave_barrier(); }

// Block barrier that drains LDS ONLY (lgkmcnt), leaving global loads in
// flight (vmcnt untouched). __syncthreads would drain vmcnt(0) and kill
// issue-early/wait-late. Functionally validated in R5.
__device__ __forceinline__ void lds_barrier(){
    asm volatile("s_waitcnt lgkmcnt(0)" ::: "memory");
    __builtin_amdgcn_s_barrier();
    asm volatile("" ::: "memory");
}

// ---------- 15-point DFT via Cooley-Tukey 3x5, all-constant twiddles ----------
template<int SIGN>
__device__ __forceinline__ void dft15(const float2* x, float2* X){
    const float S = (float)SIGN;
    const float s3 = 0.8660254037844387f;
    float2 y[5][3];
    #pragma unroll
    for (int n2 = 0; n2 < 5; ++n2){
        float2 a0 = x[n2], a1 = x[5+n2], a2 = x[10+n2];
        float2 t = cadd(a1, a2);
        float2 u = csub(a1, a2);
        float2 m = make_float2(a0.x - 0.5f*t.x, a0.y - 0.5f*t.y);
        float sx = S * s3;
        float2 s = make_float2(-sx*u.y, sx*u.x);
        y[n2][0] = cadd(a0, t);
        y[n2][1] = cadd(m, s);
        y[n2][2] = csub(m, s);
    }
    const float C15[9] = {1.f, 0.9135454576426009f, 0.6691306063588582f, 0.30901699437494745f,
                          -0.10452846326765346f, -0.5f, -0.8090169943749475f,
                          -0.9781476007338057f, -0.9781476007338057f};
    const float S15[9] = {0.f, 0.4067366430758004f, 0.7431448254773942f, 0.9510565162951535f,
                          0.9945218953682733f, 0.8660254037844387f, 0.5877852522924731f,
                          0.20791169081775931f, -0.20791169081775931f};
    #pragma unroll
    for (int n2 = 1; n2 < 5; ++n2){
        #pragma unroll
        for (int k1 = 1; k1 < 3; ++k1){
            const int e = n2*k1;
            y[n2][k1] = cmul(y[n2][k1], make_float2(C15[e], S*S15[e]));
        }
    }
    const float c1 = 0.30901699437494745f, s1 = 0.9510565162951535f;
    const float c2 = -0.8090169943749475f, s2 = 0.5877852522924731f;
    #pragma unroll
    for (int k1 = 0; k1 < 3; ++k1){
        float2 x0 = y[0][k1], x1 = y[1][k1], x2 = y[2][k1], x3 = y[3][k1], x4 = y[4][k1];
        float2 t1 = cadd(x1, x4), t3 = csub(x1, x4);
        float2 t2 = cadd(x2, x3), t4 = csub(x2, x3);
        X[k1] = make_float2(x0.x + t1.x + t2.x, x0.y + t1.y + t2.y);
        float2 u1 = make_float2(x0.x + c1*t1.x + c2*t2.x, x0.y + c1*t1.y + c2*t2.y);
        float2 u2 = make_float2(x0.x + c2*t1.x + c1*t2.x, x0.y + c2*t1.y + c1*t2.y);
        float2 v1 = make_float2(S*(s1*t3.x + s2*t4.x), S*(s1*t3.y + s2*t4.y));
        float2 v2 = make_float2(S*(s2*t3.x - s1*t4.x), S*(s2*t3.y - s1*t4.y));
        X[k1+3]  = make_float2(u1.x - v1.y, u1.y + v1.x);
        X[k1+12] = make_float2(u1.x + v1.y, u1.y - v1.x);
        X[k1+6]  = make_float2(u2.x - v2.y, u2.y + v2.x);
        X[k1+9]  = make_float2(u2.x + v2.y, u2.y - v2.x);
    }
}

// ---------- 16-point DFT via radix-4 x radix-4, all-constant twiddles ----------
template<int SIGN>
__device__ __forceinline__ void dft16(const float2* x, float2* X){
    const float S = (float)SIGN;
    float2 y[4][4];
    #pragma unroll
    for (int n2 = 0; n2 < 4; ++n2){
        float2 a0 = x[n2], a1 = x[4+n2], a2 = x[8+n2], a3 = x[12+n2];
        float2 t0 = cadd(a0,a2), t1 = csub(a0,a2);
        float2 t2 = cadd(a1,a3), t3 = csub(a1,a3);
        float2 it3 = make_float2(-S*t3.y, S*t3.x);
        y[n2][0] = cadd(t0,t2);
        y[n2][2] = csub(t0,t2);
        y[n2][1] = cadd(t1,it3);
        y[n2][3] = csub(t1,it3);
    }
    const float C16[10] = {1.f, 0.9238795325112867f, 0.7071067811865476f, 0.3826834323650898f,
                           0.f, -0.3826834323650898f, -0.7071067811865476f, -0.9238795325112867f,
                           -1.f, -0.9238795325112867f};
    const float S16[10] = {0.f, 0.3826834323650898f, 0.7071067811865476f, 0.9238795325112867f,
                           1.f, 0.9238795325112867f, 0.7071067811865476f, 0.3826834323650898f,
                           0.f, -0.3826834323650898f};
    #pragma unroll
    for (int n2 = 1; n2 < 4; ++n2){
        #pragma unroll
        for (int k1 = 1; k1 < 4; ++k1){
            const int e = n2*k1;
            y[n2][k1] = cmul(y[n2][k1], make_float2(C16[e], S*S16[e]));
        }
    }
    #pragma unroll
    for (int k1 = 0; k1 < 4; ++k1){
        float2 a0 = y[0][k1], a1 = y[1][k1], a2 = y[2][k1], a3 = y[3][k1];
        float2 t0 = cadd(a0,a2), t1 = csub(a0,a2);
        float2 t2 = cadd(a1,a3), t3 = csub(a1,a3);
        float2 it3 = make_float2(-S*t3.y, S*t3.x);
        X[k1]    = cadd(t0,t2);
        X[k1+8]  = csub(t0,t2);
        X[k1+4]  = cadd(t1,it3);
        X[k1+12] = csub(t1,it3);
    }
}

// Cooperative 240-point FFT core. v[a] = x[16a+b] preloaded in registers.
// Leaves results IN REGISTERS: for b<15, XX[m] = X[15m+b]. Row-local (rl)
// LDS exchange only => intra-wave => no block barriers inside.
template<int SIGN>
__device__ __forceinline__ void fft240_core(float2 (*sm)[PITCH], float2* v,
                                            float2* XX, int rl, int b){
    const float TWOPI = 6.28318530717958647692f;
    wave_fence();                    // order vs any prior reads of this row
    float2 Y[15];
    dft15<SIGN>(v, Y);
    float2 step, tw = make_float2(1.0f, 0.0f);
    {
        float ang = (float)SIGN * TWOPI * (float)b * (1.0f/240.0f);
        __sincosf(ang, &step.y, &step.x);
    }
    #pragma unroll
    for (int d = 0; d < 15; ++d){
        sm[rl][b*15 + d] = cmul(Y[d], tw);
        tw = cmul(tw, step);
    }
    wave_fence();
    float2 Z[16];
    if (b < 15){
        #pragma unroll
        for (int bb = 0; bb < 16; ++bb) Z[bb] = sm[rl][bb*15 + b];
    }
    wave_fence();                    // gathers complete before row is reused
    if (b < 15) dft16<SIGN>(Z, XX);
}

// Full FFT: core + scatter so sm[rl][k] = X[k] (passA's Hermitian unpack
// needs cross-lane access to X[240-k]).
template<int SIGN>
__device__ __forceinline__ void fft240(float2 (*sm)[PITCH], float2* v, int rl, int b){
    float2 XX[16];
    fft240_core<SIGN>(sm, v, XX, rl, b);
    if (b < 15){
        #pragma unroll
        for (int m = 0; m < 16; ++m) sm[rl][15*m + b] = XX[m];
    }
    wave_fence();
}

// Pass A (REAL-PACKED, PIPELINED, ZERO BARRIERS): CHA chunks of 30 real rows
// per block; rows 2r->Re, 2r+1->Im; direct coalesced global->reg loads, next
// chunk prefetched during current FFT. Hermitian unpack is exact.
__global__ __launch_bounds__(256) void passA_rowfft(const float* __restrict__ x,
                                                    __half2* __restrict__ out){
    __shared__ __align__(16) float2 sm[15][PITCH];
    int g = blockIdx.x;
    int tid = threadIdx.x, rl = tid >> 4, b = tid & 15;
    if (tid >= 240) return;                 // no block barriers: safe
    float2 v[15];
    {
        int c = g*CHA; int img = c / NBA, h0 = (c % NBA) * 30;
        const float* r0 = x + (size_t)img * IMG_PIX + (size_t)(h0 + 2*rl) * HW;
        #pragma unroll
        for (int a = 0; a < 15; ++a)
            v[a] = make_float2(r0[16*a + b], r0[HW + 16*a + b]);
    }
    for (int t = 0; t < CHA; ++t){
        int c = g*CHA + t; int img = c / NBA, h0 = (c % NBA) * 30;
        float2 nv[15];
        if (t+1 < CHA){                     // prefetch next chunk early
            int c2 = c + 1; int img2 = c2 / NBA, h02 = (c2 % NBA) * 30;
            const float* r0 = x + (size_t)img2 * IMG_PIX + (size_t)(h02 + 2*rl) * HW;
            #pragma unroll
            for (int a = 0; a < 15; ++a)
                nv[a] = make_float2(r0[16*a + b], r0[HW + 16*a + b]);
        }
        asm volatile("" ::: "memory");      // pin prefetch issue point
        fft240<-1>(sm, v, rl, b);           // sm[rl][k] = packed spectrum
        #pragma unroll
        for (int kb = 0; kb < NB; ++kb){
            int k = kb*16 + b;
            int km = k ? 240 - k : 0;
            float2 P = sm[rl][k], Q = sm[rl][km];   // own row: intra-wave
            float2 Xa = make_float2(0.5f*(P.x + Q.x), 0.5f*(P.y - Q.y));
            float2 Xb = make_float2(0.5f*(P.y + Q.y), 0.5f*(Q.x - P.x));
            size_t o = ((size_t)(img*NB + kb)*HW + (h0 + 2*rl))*16 + b;
            out[o]      = f2h(Xa);          // row h0+2rl
            out[o + 16] = f2h(Xb);          // row h0+2rl+1
        }
        if (t+1 < CHA){
            #pragma unroll
            for (int a = 0; a < 15; ++a) v[a] = nv[a];
        }
    }
}

// Pass B (IN-PLACE, single chunk/block, R2 structure): coalesced float4 stage
// -> LDS; lgkm-only barriers; U tile prefetched (issue-early, wait at combine);
// LDS-RMW combine with coalesced U pattern; direct in-reg stores (no B4).
__global__ __launch_bounds__(256) void passB_col_dc_icol(__half2* __restrict__ io,
                                                         const float* __restrict__ under,
                                                         const float* __restrict__ Am){
    __shared__ __align__(16) float2 sm[16][PITCH];
    int g = blockIdx.x, img = g / NB, s = g % NB, kw0 = s * 16;
    int tid = threadIdx.x, rl = tid >> 4, b = tid & 15;
    __half2* chunk = io + (size_t)(img*NB + s) * TILE_ELEMS;   // [h][c]

    // coalesced float4 stage -> LDS (R2-proven pattern)
    if (tid < 240){
        #pragma unroll
        for (int jj = 0; jj < 4; ++jj){
            int k = jj*240 + tid;
            float4 raw = *(const float4*)(chunk + 4*k);   // 4 half2 = 16 B
            const __half2* hp = (const __half2*)&raw;
            int col = k >> 2;
            int r0 = (4*k) & 15;
            #pragma unroll
            for (int i = 0; i < 4; ++i) sm[r0 + i][col] = h2f(hp[i]);
        }
    }
    // issue U prefetch NOW; vmcnt wait lands at the combine (~2 FFTs later).
    // lgkm-only barriers keep these in flight.
    const float* y0 = under + (size_t)img * (2*IMG_PIX);
    float y0r[15], y1r[15];
    #pragma unroll
    for (int j = 0; j < 15; ++j){
        size_t p = (size_t)(j*16 + rl) * HW + kw0 + b;   // coalesced 64B/16 lanes
        y0r[j] = y0[p];
        y1r[j] = y0[IMG_PIX + p];
    }
    asm volatile("" ::: "memory");        // pin issue point (no sinking)
    lds_barrier();                        // B1: stage visible
    float2 v[15];
    #pragma unroll
    for (int a = 0; a < 15; ++a) v[a] = sm[rl][16*a + b];
    float2 XX[16];
    fft240_core<-1>(sm, v, XX, rl, b);    // XX[m] = X[kh=15m+b], col kw0+rl
    if (b < 15){
        #pragma unroll
        for (int m = 0; m < 16; ++m) sm[rl][15*m + b] = XX[m];
    }
    lds_barrier();                        // B2: spectrum visible cross-wave
    #pragma unroll
    for (int j = 0; j < 15; ++j){         // DC combine, coalesced U pattern
        int kh = j*16 + rl;
        size_t p = (size_t)kh * HW + kw0 + b;
        float sc = 1.0f - Am[p];
        float2 X = sm[b][kh];
        sm[b][kh] = make_float2(sc * X.x + y0r[j], sc * X.y + y1r[j]);
    }
    lds_barrier();                        // B3: combine visible cross-wave
    float2 v2[15];
    #pragma unroll
    for (int a = 0; a < 15; ++a) v2[a] = sm[rl][16*a + b];
    float2 ZZ[16];
    fft240_core<+1>(sm, v2, ZZ, rl, b);   // ZZ[m] = 240*z[h=15m+b], col rl
    const float inv240 = 1.0f / 240.0f;
    if (b < 15){                          // direct in-reg store (L2 merges;
        #pragma unroll                    // validated R4/R5: WRITE_SIZE ideal)
        for (int m = 0; m < 16; ++m)
            chunk[(size_t)(15*m + b)*16 + rl] =
                f2h(make_float2(ZZ[m].x*inv240, ZZ[m].y*inv240));
    }
}

// Pass C (PIPELINED, ZERO BARRIERS): CHC row tiles per block; direct coalesced
// global->reg gather across the 15 chunks, inverse row FFT, abs*1/240, direct
// reg->global store; next tile prefetched during current FFT.
__global__ __launch_bounds__(256) void passC_irow_abs(const __half2* __restrict__ in,
                                                      float* __restrict__ outp){
    __shared__ __align__(16) float2 sm[16][PITCH];
    int g = blockIdx.x;
    int tid = threadIdx.x, rl = tid >> 4, b = tid & 15;
    float2 v[15];
    {
        int c = g*CHC; int img = c / NB, h0 = (c % NB) * 16;
        #pragma unroll
        for (int a = 0; a < 15; ++a)
            v[a] = h2f(in[((size_t)(img*NB + a)*HW + h0 + rl)*16 + b]);
    }
    const float inv240 = 1.0f / 240.0f;
    for (int t = 0; t < CHC; ++t){
        int c = g*CHC + t; int img = c / NB, h0 = (c % NB) * 16;
        float2 nv[15];
        if (t+1 < CHC){                     // prefetch next tile early
            int c2 = c + 1; int img2 = c2 / NB, h02 = (c2 % NB) * 16;
            #pragma unroll
            for (int a = 0; a < 15; ++a)
                nv[a] = h2f(in[((size_t)(img2*NB + a)*HW + h02 + rl)*16 + b]);
        }
        asm volatile("" ::: "memory");      // pin prefetch issue point
        float2 XX[16];
        fft240_core<+1>(sm, v, XX, rl, b);  // XX[m] = 240*z[w=15m+b], row h0+rl
        float* dst = outp + (size_t)img * IMG_PIX + (size_t)(h0 + rl) * HW;
        if (b < 15){
            #pragma unroll
            for (int m = 0; m < 16; ++m){
                float2 X = XX[m];
                dst[15*m + b] = sqrtf(X.x*X.x + X.y*X.y) * inv240;
            }
        }
        if (t+1 < CHC){
            #pragma unroll
            for (int a = 0; a < 15; ++a) v[a] = nv[a];
        }
    }
}

extern "C" void kernel_launch(void* const* d_in, const int* in_sizes, int n_in,
                              void* d_out, int out_size, void* d_ws, size_t ws_size,
                              hipStream_t stream){
    const float* T2   = (const float*)d_in[0];   // [256,1,240,240] f32
    const float* U    = (const float*)d_in[1];   // [256,2,240,240] f32
    const float* Am   = (const float*)d_in[2];   // [240,240] f32
    float* out        = (float*)d_out;           // [256,1,240,240] f32

    const int B = 256;
    __half2* i1 = (__half2*)d_ws;                // single 59 MB fp16 intermediate

    dim3 block(256);
    passA_rowfft     <<<dim3(B * NBA / CHA), block, 0, stream>>>(T2, i1);
    passB_col_dc_icol<<<dim3(B * NB),        block, 0, stream>>>(i1, U, Am);
    passC_irow_abs   <<<dim3(B * NB / CHC),  block, 0, stream>>>(i1, out);
}

// Round 7
// 274.099 us; speedup vs baseline: 1.2645x; 1.0732x over previous
//
#include <hip/hip_runtime.h>
#include <hip/hip_fp16.h>
#include <math.h>

#define HW 240
#define PITCH 242           // complex pitch (float4-aligned rows)
#define IMG_PIX (HW*HW)     // 57600
#define NB 15               // 16-wide blocks per image (all passes)
#define TILE_ELEMS (240*16) // elements per blocked chunk
#define CHC 3               // chunks per block, passC  (3840/3 = 1280 blocks)

__device__ __forceinline__ float2 cmul(float2 a, float2 b){
    return make_float2(a.x*b.x - a.y*b.y, a.x*b.y + a.y*b.x);
}
__device__ __forceinline__ float2 cadd(float2 a, float2 b){
    return make_float2(a.x+b.x, a.y+b.y);
}
__device__ __forceinline__ float2 csub(float2 a, float2 b){
    return make_float2(a.x-b.x, a.y-b.y);
}
__device__ __forceinline__ __half2 f2h(float2 a){ return __floats2half2_rn(a.x, a.y); }
__device__ __forceinline__ float2 h2f(__half2 h){ return make_float2(__low2float(h), __high2float(h)); }

// Compiler-only fence: a wave's DS ops execute in issue order on the DS pipe,
// so intra-wave LDS exchanges need no s_barrier (validated R2-R6 on this fft).
__device__ __forceinline__ void wave_fence(){ __builtin_amdgcn_wave_barrier(); }

// Block barrier that drains LDS ONLY (lgkmcnt), leaving global loads in
// flight (vmcnt untouched). Functionally validated R5/R6.
__device__ __forceinline__ void lds_barrier(){
    asm volatile("s_waitcnt lgkmcnt(0)" ::: "memory");
    __builtin_amdgcn_s_barrier();
    asm volatile("" ::: "memory");
}

// ---------- 15-point DFT via Cooley-Tukey 3x5, all-constant twiddles ----------
template<int SIGN>
__device__ __forceinline__ void dft15(const float2* x, float2* X){
    const float S = (float)SIGN;
    const float s3 = 0.8660254037844387f;
    float2 y[5][3];
    #pragma unroll
    for (int n2 = 0; n2 < 5; ++n2){
        float2 a0 = x[n2], a1 = x[5+n2], a2 = x[10+n2];
        float2 t = cadd(a1, a2);
        float2 u = csub(a1, a2);
        float2 m = make_float2(a0.x - 0.5f*t.x, a0.y - 0.5f*t.y);
        float sx = S * s3;
        float2 s = make_float2(-sx*u.y, sx*u.x);
        y[n2][0] = cadd(a0, t);
        y[n2][1] = cadd(m, s);
        y[n2][2] = csub(m, s);
    }
    const float C15[9] = {1.f, 0.9135454576426009f, 0.6691306063588582f, 0.30901699437494745f,
                          -0.10452846326765346f, -0.5f, -0.8090169943749475f,
                          -0.9781476007338057f, -0.9781476007338057f};
    const float S15[9] = {0.f, 0.4067366430758004f, 0.7431448254773942f, 0.9510565162951535f,
                          0.9945218953682733f, 0.8660254037844387f, 0.5877852522924731f,
                          0.20791169081775931f, -0.20791169081775931f};
    #pragma unroll
    for (int n2 = 1; n2 < 5; ++n2){
        #pragma unroll
        for (int k1 = 1; k1 < 3; ++k1){
            const int e = n2*k1;
            y[n2][k1] = cmul(y[n2][k1], make_float2(C15[e], S*S15[e]));
        }
    }
    const float c1 = 0.30901699437494745f, s1 = 0.9510565162951535f;
    const float c2 = -0.8090169943749475f, s2 = 0.5877852522924731f;
    #pragma unroll
    for (int k1 = 0; k1 < 3; ++k1){
        float2 x0 = y[0][k1], x1 = y[1][k1], x2 = y[2][k1], x3 = y[3][k1], x4 = y[4][k1];
        float2 t1 = cadd(x1, x4), t3 = csub(x1, x4);
        float2 t2 = cadd(x2, x3), t4 = csub(x2, x3);
        X[k1] = make_float2(x0.x + t1.x + t2.x, x0.y + t1.y + t2.y);
        float2 u1 = make_float2(x0.x + c1*t1.x + c2*t2.x, x0.y + c1*t1.y + c2*t2.y);
        float2 u2 = make_float2(x0.x + c2*t1.x + c1*t2.x, x0.y + c2*t1.y + c1*t2.y);
        float2 v1 = make_float2(S*(s1*t3.x + s2*t4.x), S*(s1*t3.y + s2*t4.y));
        float2 v2 = make_float2(S*(s2*t3.x - s1*t4.x), S*(s2*t3.y - s1*t4.y));
        X[k1+3]  = make_float2(u1.x - v1.y, u1.y + v1.x);
        X[k1+12] = make_float2(u1.x + v1.y, u1.y - v1.x);
        X[k1+6]  = make_float2(u2.x - v2.y, u2.y + v2.x);
        X[k1+9]  = make_float2(u2.x + v2.y, u2.y - v2.x);
    }
}

// ---------- 16-point DFT via radix-4 x radix-4, all-constant twiddles ----------
template<int SIGN>
__device__ __forceinline__ void dft16(const float2* x, float2* X){
    const float S = (float)SIGN;
    float2 y[4][4];
    #pragma unroll
    for (int n2 = 0; n2 < 4; ++n2){
        float2 a0 = x[n2], a1 = x[4+n2], a2 = x[8+n2], a3 = x[12+n2];
        float2 t0 = cadd(a0,a2), t1 = csub(a0,a2);
        float2 t2 = cadd(a1,a3), t3 = csub(a1,a3);
        float2 it3 = make_float2(-S*t3.y, S*t3.x);
        y[n2][0] = cadd(t0,t2);
        y[n2][2] = csub(t0,t2);
        y[n2][1] = cadd(t1,it3);
        y[n2][3] = csub(t1,it3);
    }
    const float C16[10] = {1.f, 0.9238795325112867f, 0.7071067811865476f, 0.3826834323650898f,
                           0.f, -0.3826834323650898f, -0.7071067811865476f, -0.9238795325112867f,
                           -1.f, -0.9238795325112867f};
    const float S16[10] = {0.f, 0.3826834323650898f, 0.7071067811865476f, 0.9238795325112867f,
                           1.f, 0.9238795325112867f, 0.7071067811865476f, 0.3826834323650898f,
                           0.f, -0.3826834323650898f};
    #pragma unroll
    for (int n2 = 1; n2 < 4; ++n2){
        #pragma unroll
        for (int k1 = 1; k1 < 4; ++k1){
            const int e = n2*k1;
            y[n2][k1] = cmul(y[n2][k1], make_float2(C16[e], S*S16[e]));
        }
    }
    #pragma unroll
    for (int k1 = 0; k1 < 4; ++k1){
        float2 a0 = y[0][k1], a1 = y[1][k1], a2 = y[2][k1], a3 = y[3][k1];
        float2 t0 = cadd(a0,a2), t1 = csub(a0,a2);
        float2 t2 = cadd(a1,a3), t3 = csub(a1,a3);
        float2 it3 = make_float2(-S*t3.y, S*t3.x);
        X[k1]    = cadd(t0,t2);
        X[k1+8]  = csub(t0,t2);
        X[k1+4]  = cadd(t1,it3);
        X[k1+12] = csub(t1,it3);
    }
}

// Cooperative 240-point FFT core. v[a] = x[16a+b] preloaded in registers.
// Leaves results IN REGISTERS: for b<15, XX[m] = X[15m+b]. Row-local (rl)
// LDS exchange only => intra-wave => no block barriers inside.
template<int SIGN>
__device__ __forceinline__ void fft240_core(float2 (*sm)[PITCH], float2* v,
                                            float2* XX, int rl, int b){
    const float TWOPI = 6.28318530717958647692f;
    wave_fence();                    // order vs any prior reads of this row
    float2 Y[15];
    dft15<SIGN>(v, Y);
    float2 step, tw = make_float2(1.0f, 0.0f);
    {
        float ang = (float)SIGN * TWOPI * (float)b * (1.0f/240.0f);
        __sincosf(ang, &step.y, &step.x);
    }
    #pragma unroll
    for (int d = 0; d < 15; ++d){
        sm[rl][b*15 + d] = cmul(Y[d], tw);
        tw = cmul(tw, step);
    }
    wave_fence();
    float2 Z[16];
    if (b < 15){
        #pragma unroll
        for (int bb = 0; bb < 16; ++bb) Z[bb] = sm[rl][bb*15 + b];
    }
    wave_fence();                    // gathers complete before row is reused
    if (b < 15) dft16<SIGN>(Z, XX);
}

// Full FFT: core + scatter so sm[rl][k] = X[k] (passA's Hermitian unpack
// needs cross-lane access to X[240-k]).
template<int SIGN>
__device__ __forceinline__ void fft240(float2 (*sm)[PITCH], float2* v, int rl, int b){
    float2 XX[16];
    fft240_core<SIGN>(sm, v, XX, rl, b);
    if (b < 15){
        #pragma unroll
        for (int m = 0; m < 16; ++m) sm[rl][15*m + b] = XX[m];
    }
    wave_fence();
}

// Intermediate layout L (passB-input-ready), per (img, s, 16-row group A):
//   idx = ((img*15 + s)*15 + A)*256 + c*16 + (h&15),   kw = s*16 + c.
// passB reads v[a] = L[a*256 + rl*16 + b]  -> 256B/wave contiguous, no stage.

// Pass A (REAL-PACKED, 128 threads, one 16-row group per block): 8 packed
// complex FFTs (rows 2r->Re, 2r+1->Im), exact Hermitian unpack to registers,
// LDS transpose to L-tile, fully-coalesced dwordx4 stores.
__global__ __launch_bounds__(128) void passA_rowfft(const float* __restrict__ x,
                                                    __half2* __restrict__ out){
    __shared__ __align__(16) float2 smbuf[8*PITCH];   // 15.1 KB, aliased below
    float2 (*sm)[PITCH] = (float2(*)[PITCH])smbuf;
    __half2* Lh = (__half2*)smbuf;                    // 3840 half2 = 15 KB
    int g = blockIdx.x, img = g / NB, Ag = g % NB, h0 = Ag * 16;
    int tid = threadIdx.x, rl = tid >> 4, b = tid & 15;   // rl in [0,8)
    const float* r0 = x + (size_t)img * IMG_PIX + (size_t)(h0 + 2*rl) * HW;
    float2 v[15];
    #pragma unroll
    for (int a = 0; a < 15; ++a)
        v[a] = make_float2(r0[16*a + b], r0[HW + 16*a + b]);
    fft240<-1>(sm, v, rl, b);               // sm[rl][k] = packed spectrum
    __half2 xa[15], xb[15];
    #pragma unroll
    for (int kb = 0; kb < NB; ++kb){
        int k = kb*16 + b;
        int km = k ? 240 - k : 0;
        float2 P = sm[rl][k], Q = sm[rl][km];   // own row: intra-wave
        xa[kb] = f2h(make_float2(0.5f*(P.x + Q.x), 0.5f*(P.y - Q.y)));  // row h0+2rl
        xb[kb] = f2h(make_float2(0.5f*(P.y + Q.y), 0.5f*(Q.x - P.x)));  // row h0+2rl+1
    }
    lds_barrier();                          // all unpack reads done; alias sm->Lh
    #pragma unroll
    for (int kb = 0; kb < NB; ++kb){        // L-tile: [s=kb][c=b][bb=2rl,2rl+1]
        Lh[kb*256 + b*16 + 2*rl]     = xa[kb];
        Lh[kb*256 + b*16 + 2*rl + 1] = xb[kb];
    }
    lds_barrier();                          // L-tile built
    float4* gout = (float4*)out;
    #pragma unroll
    for (int i = 0; i < 8; ++i){            // 960 float4 units, coalesced
        int u = i*128 + tid;
        if (u < 960){
            int seg = u >> 6, e = u & 63;   // 64 float4 per s-segment
            gout[((size_t)(img*NB + seg)*NB + Ag)*64 + e] = ((float4*)Lh)[u];
        }
    }
}

// Pass B (IN-PLACE, NO STAGE): direct coalesced reg-gather from layout L,
// forward col FFT, R2's LDS-RMW combine (coalesced U/Am reads), inverse col
// FFT, R2's staged float4 store in [h][c] order for passC. 3 lgkm barriers.
__global__ __launch_bounds__(256) void passB_col_dc_icol(__half2* __restrict__ io,
                                                         const float* __restrict__ under,
                                                         const float* __restrict__ Am){
    __shared__ __align__(16) float2 sm[16][PITCH];
    int g = blockIdx.x, img = g / NB, s = g % NB, kw0 = s * 16;
    int tid = threadIdx.x, rl = tid >> 4, b = tid & 15;
    __half2* chunk = io + (size_t)(img*NB + s) * TILE_ELEMS;

    float2 v[15];                           // v[a] = element (h=16a+b, kw=kw0+rl)
    #pragma unroll
    for (int a = 0; a < 15; ++a)
        v[a] = h2f(chunk[a*256 + rl*16 + b]);   // 256B/wave contiguous

    float2 XX[16];
    fft240_core<-1>(sm, v, XX, rl, b);      // XX[m] = X[kh=15m+b], col kw0+rl
    if (b < 15){
        #pragma unroll
        for (int m = 0; m < 16; ++m) sm[rl][15*m + b] = XX[m];   // sm[c][kh]
    }
    lds_barrier();                          // B2: spectrum visible cross-wave
    const float* y0 = under + (size_t)img * (2*IMG_PIX);
    #pragma unroll
    for (int j = 0; j < 15; ++j){           // DC combine, coalesced U/Am reads
        int kh = j*16 + rl;
        size_t p = (size_t)kh * HW + kw0 + b;
        float sc = 1.0f - Am[p];
        float2 X = sm[b][kh];
        sm[b][kh] = make_float2(sc * X.x + y0[p], sc * X.y + y0[IMG_PIX + p]);
    }
    lds_barrier();                          // B3: combine visible cross-wave
    float2 v2[15];
    #pragma unroll
    for (int a = 0; a < 15; ++a) v2[a] = sm[rl][16*a + b];
    float2 ZZ[16];
    fft240_core<+1>(sm, v2, ZZ, rl, b);     // ZZ[m] = 240*z[h=15m+b], col rl
    const float inv240 = 1.0f / 240.0f;
    if (b < 15){                            // own-row scatter (DS-order safe)
        #pragma unroll
        for (int m = 0; m < 16; ++m)
            sm[rl][15*m + b] = make_float2(ZZ[m].x*inv240, ZZ[m].y*inv240);
    }
    lds_barrier();                          // B4: tile complete
    if (tid < 240){                         // staged float4 store, [h][c] order
        #pragma unroll
        for (int jj = 0; jj < 4; ++jj){
            int k = jj*240 + tid;
            int col = k >> 2;
            int r0 = (4*k) & 15;
            float4 outv;
            __half2* op = (__half2*)&outv;
            #pragma unroll
            for (int i = 0; i < 4; ++i) op[i] = f2h(sm[r0 + i][col]);
            *(float4*)(chunk + 4*k) = outv;  // 16 B/lane contiguous
        }
    }
}

// Pass C (PIPELINED, ZERO BARRIERS, unchanged): direct coalesced global->reg
// gather across the 15 [h][c] chunks, inverse row FFT, abs*1/240, store.
__global__ __launch_bounds__(256) void passC_irow_abs(const __half2* __restrict__ in,
                                                      float* __restrict__ outp){
    __shared__ __align__(16) float2 sm[16][PITCH];
    int g = blockIdx.x;
    int tid = threadIdx.x, rl = tid >> 4, b = tid & 15;
    float2 v[15];
    {
        int c = g*CHC; int img = c / NB, h0 = (c % NB) * 16;
        #pragma unroll
        for (int a = 0; a < 15; ++a)
            v[a] = h2f(in[((size_t)(img*NB + a)*HW + h0 + rl)*16 + b]);
    }
    const float inv240 = 1.0f / 240.0f;
    for (int t = 0; t < CHC; ++t){
        int c = g*CHC + t; int img = c / NB, h0 = (c % NB) * 16;
        float2 nv[15];
        if (t+1 < CHC){                     // prefetch next tile early
            int c2 = c + 1; int img2 = c2 / NB, h02 = (c2 % NB) * 16;
            #pragma unroll
            for (int a = 0; a < 15; ++a)
                nv[a] = h2f(in[((size_t)(img2*NB + a)*HW + h02 + rl)*16 + b]);
        }
        asm volatile("" ::: "memory");      // pin prefetch issue point
        float2 XX[16];
        fft240_core<+1>(sm, v, XX, rl, b);  // XX[m] = 240*z[w=15m+b], row h0+rl
        float* dst = outp + (size_t)img * IMG_PIX + (size_t)(h0 + rl) * HW;
        if (b < 15){
            #pragma unroll
            for (int m = 0; m < 16; ++m){
                float2 X = XX[m];
                dst[15*m + b] = sqrtf(X.x*X.x + X.y*X.y) * inv240;
            }
        }
        if (t+1 < CHC){
            #pragma unroll
            for (int a = 0; a < 15; ++a) v[a] = nv[a];
        }
    }
}

extern "C" void kernel_launch(void* const* d_in, const int* in_sizes, int n_in,
                              void* d_out, int out_size, void* d_ws, size_t ws_size,
                              hipStream_t stream){
    const float* T2   = (const float*)d_in[0];   // [256,1,240,240] f32
    const float* U    = (const float*)d_in[1];   // [256,2,240,240] f32
    const float* Am   = (const float*)d_in[2];   // [240,240] f32
    float* out        = (float*)d_out;           // [256,1,240,240] f32

    const int B = 256;
    __half2* i1 = (__half2*)d_ws;                // single 59 MB fp16 intermediate

    passA_rowfft     <<<dim3(B * NB),       dim3(128), 0, stream>>>(T2, i1);
    passB_col_dc_icol<<<dim3(B * NB),       dim3(256), 0, stream>>>(i1, U, Am);
    passC_irow_abs   <<<dim3(B * NB / CHC), dim3(256), 0, stream>>>(i1, out);
}